// Round 7
// baseline (969.268 us; speedup 1.0000x reference)
//
#include <hip/hip_runtime.h>
#include <hip/hip_bf16.h>

#define NCH 256
#define VEC 32896   // 256*257/2

typedef __attribute__((ext_vector_type(4)))  float f32x4;
typedef __attribute__((ext_vector_type(8)))  short short8;
typedef __attribute__((ext_vector_type(32))) float f32x32;
typedef __attribute__((ext_vector_type(4)))  unsigned short u16x4;
typedef __attribute__((ext_vector_type(4), aligned(4))) float f32x4u;  // 4B-aligned float4

template <int C>
__device__ __forceinline__ f32x32& sel2(f32x32& a, f32x32& b) {
    if constexpr (C == 0) return a; else return b;
}

__device__ __forceinline__ void load_chunk(f32x32& V, const float* src) {
#pragma unroll
    for (int k = 0; k < 32; k += 4) {
        const float4 q = *reinterpret_cast<const float4*>(src + k);
        V[k] = q.x; V[k + 1] = q.y; V[k + 2] = q.z; V[k + 3] = q.w;
    }
}

// trailing rank-32 update of one owned chunk (gc = q or q+4, wave-uniform)
template <int IDX, int P>
__device__ __forceinline__ void trail2(f32x32& V, const f32x32& Lr,
                                       const float (&Ap)[256][34],
                                       int q, int band, bool below) {
    const int gc = (IDX == 0) ? q : q + 4;
    if (gc >= P + 1 && gc <= 2 * band + 1) {   // wave-uniform
        if (below) {                            // per-lane
#pragma unroll
            for (int k = 0; k < 32; ++k) {
                float acc = V[k];
                const float* rowp = Ap[gc * 32 + k];
#pragma unroll
                for (int u = 0; u < 32; u += 2) {
                    const float2 pv = *reinterpret_cast<const float2*>(rowp + u);
                    acc = fmaf(-Lr[u],     pv.x, acc);
                    acc = fmaf(-Lr[u + 1], pv.y, acc);
                }
                V[k] = acc;
            }
        }
    }
}

// one panel step, fully inlined (round-5/6 lesson: anything that blocks SROA
// puts the row state in scratch; round-6 lesson: allocator won't exceed 128
// VGPR, so per-thread state must fit under it -> 2 chunks/thread)
template <int P>
__device__ __forceinline__ void panel_step(
        float* __restrict__ tv, float (&Ap)[256][34], float (&Dblk)[32][34],
        float (&Dinv)[32], f32x32& v0, f32x32& v1,
        int t, int lane, int q, int band, int i) {
    constexpr int qo = P & 3, lc = P >> 2, pbase = P << 5;

    // --- 1. owner publishes diag block (rows 32P..32P+31, chunk P) ---
    if (q == qo && (i >> 5) == P) {
        const int r = i & 31;
        f32x32& V = sel2<lc>(v0, v1);
#pragma unroll
        for (int k = 0; k < 32; ++k) Dblk[r][k] = V[k];
    }
    __syncthreads();

    // --- 2. factor 32x32 diag block in wave 0 (lane pairs mirror rows) ---
    if (t < 64) {
        const int r = lane & 31;
        f32x32 a;
#pragma unroll
        for (int k = 0; k < 32; ++k) a[k] = Dblk[r][k];
        float mydiag = 1.0f;
#pragma unroll
        for (int j = 0; j < 32; ++j) {
            const float dj  = __shfl(a[j], j);
            const float d   = sqrtf(dj);
            const float inv = 1.0f / d;
            const float lrj = a[j] * inv;
            a[j] = (r == j) ? d : lrj;           // garbage for r<j (finite)
            if (r == j) mydiag = d;
#pragma unroll
            for (int k = j + 1; k < 32; ++k) {
                const float lkj = __shfl(a[j], k);
                a[k] = fmaf(-a[j], lkj, a[k]);
            }
        }
        if (lane < 32) {
            const int gr = pbase + r;
            const int tb = gr * (gr + 1) / 2 + pbase;
#pragma unroll
            for (int k = 0; k < 32; ++k) {
                Dblk[r][k] = a[k];
                if (k < r) tv[tb + k] = a[k];
            }
            Dinv[r] = 1.0f / mydiag;
            const float x = mydiag - 1e-5f;
            tv[tb + r] = x + logf(-expm1f(-x));  // softplus_inverse
        }
    }
    __syncthreads();

    // --- 3. TRSM rows below panel (owner q), publish to Ap + t ---
    const bool below = (i >= pbase + 32);
    if (q == qo && below) {
        f32x32& V = sel2<lc>(v0, v1);
#pragma unroll
        for (int k = 0; k < 32; ++k) {
            float xk = V[k];
#pragma unroll
            for (int u = 0; u < k; ++u) xk = fmaf(-V[u], Dblk[k][u], xk);
            V[k] = xk * Dinv[k];
        }
        const int tb = i * (i + 1) / 2 + pbase;
#pragma unroll
        for (int k = 0; k < 32; ++k) { Ap[i][k] = V[k]; tv[tb + k] = V[k]; }
    }
    __syncthreads();

    // --- 4. trailing rank-32 update of owned chunks ---
    {
        f32x32 Lr;
        if (below) {
            if (q == qo) {
                Lr = sel2<lc>(v0, v1);
            } else {
#pragma unroll
                for (int k = 0; k < 32; ++k) Lr[k] = Ap[i][k];
            }
        }
        trail2<0, P>(v0, Lr, Ap, q, band, below);
        trail2<1, P>(v1, Lr, Ap, q, band, below);
    }
    __syncthreads();
}

// ---------------------------------------------------------------------------
// Stage 1: blocked panel Cholesky (panel width 32) + FillScaleTriL inverse.
// 1024 threads: 4 threads per row (q = 0..3), each owning chunks {q, q+4}
// (64 floats of register state -> fits the 128-VGPR budget with no spill).
// Per panel: in-wave diag factor (shfl), owner TRSM, rank-32 trailing update.
// ---------------------------------------------------------------------------
__global__ void __launch_bounds__(1024)
chol_kernel(const float* __restrict__ G, float* __restrict__ t_out) {
    const int t    = threadIdx.x;
    const int w    = t >> 6;
    const int lane = t & 63;
    const int q    = w >> 2;                    // chunk-owner group 0..3
    const int band = (w & 3) ^ (w >> 2);        // row band 0..3 (SIMD-mixing)
    const int i    = band * 64 + lane;          // my row

    const float* A  = G + (size_t)blockIdx.x * NCH * NCH;
    float*       tv = t_out + (size_t)blockIdx.x * VEC;

    __shared__ float Ap[256][34];    // published panel L (pad 34: conflict-light)
    __shared__ float Dblk[32][34];   // diag block / L_pp
    __shared__ float Dinv[32];

    f32x32 v0, v1;                   // chunks gc=q (cols 32q..) and gc=q+4
    {
        const float* base = A + (size_t)i * NCH + q * 32;
        load_chunk(v0, base);
        load_chunk(v1, base + 128);
    }

    panel_step<0>(tv, Ap, Dblk, Dinv, v0, v1, t, lane, q, band, i);
    panel_step<1>(tv, Ap, Dblk, Dinv, v0, v1, t, lane, q, band, i);
    panel_step<2>(tv, Ap, Dblk, Dinv, v0, v1, t, lane, q, band, i);
    panel_step<3>(tv, Ap, Dblk, Dinv, v0, v1, t, lane, q, band, i);
    panel_step<4>(tv, Ap, Dblk, Dinv, v0, v1, t, lane, q, band, i);
    panel_step<5>(tv, Ap, Dblk, Dinv, v0, v1, t, lane, q, band, i);
    panel_step<6>(tv, Ap, Dblk, Dinv, v0, v1, t, lane, q, band, i);
    panel_step<7>(tv, Ap, Dblk, Dinv, v0, v1, t, lane, q, band, i);
}

// ---------------------------------------------------------------------------
// Stage 2: per (s,m): L = tril(t + dev_perm) with softplus diag; C = L*L^T+eps.
// Vectorized staging; L in LDS as bf16 (swizzled); MFMA with cached A-frags.
// (Unchanged: waiting for its first counter rows before editing.)
// ---------------------------------------------------------------------------
__global__ __launch_bounds__(1024)
void syrk_kernel(const float* __restrict__ dev, const float* __restrict__ t_in,
                 float* __restrict__ out) {
    extern __shared__ char smem[];             // 131072 B: bf16 L[256][256], swizzled
    const int bid  = blockIdx.x;               // s*8 + m
    const int m    = bid & 7;
    const int tid  = threadIdx.x;
    const int lane = tid & 63;
    const int w    = tid >> 6;                 // 16 waves

    const float* dv = dev  + (size_t)bid * VEC;
    const float* tv = t_in + (size_t)m * VEC;
    float* C = out + (size_t)bid * NCH * NCH;

    // ---- stage L into LDS (one row per wave per iteration; float4 loads) ----
#pragma unroll 4
    for (int it = 0; it < 16; ++it) {
        const int pos = it * 4096 + tid * 4;   // r = it*16 + w (wave-uniform)
        const int r  = pos >> 8;
        const int c0 = pos & 255;              // lane*4
        u16x4 ov = {0, 0, 0, 0};
        if (c0 <= r) {
            float4 dvv;
            if (r < 128) {
                dvv = *reinterpret_cast<const float4*>(dv + pos + 256);
            } else {
                const float4 t4 = *reinterpret_cast<const float4*>(dv + (65532 - pos));
                dvv.x = t4.w; dvv.y = t4.z; dvv.z = t4.y; dvv.w = t4.x;
            }
            const int s0 = r * (r + 1) / 2 + c0;
            const f32x4u tvv = *reinterpret_cast<const f32x4u*>(tv + s0);
            const float dva[4] = {dvv.x, dvv.y, dvv.z, dvv.w};
#pragma unroll
            for (int j = 0; j < 4; ++j) {
                const int c = c0 + j;
                if (c <= r) {
                    float u = tvv[j] + dva[j];
                    if (c == r) {
                        u = (u > 20.0f) ? u : log1pf(expf(u));   // softplus
                        u += 1e-5f;                              // diag_shift
                    }
                    __hip_bfloat16 hb = __float2bfloat16(u);
                    ov[j] = *reinterpret_cast<unsigned short*>(&hb);
                }
            }
        }
        int byte = (r << 9) + (c0 << 1);
        byte ^= (r & 7) << 4;                  // bank-conflict swizzle (8B-align safe)
        *reinterpret_cast<u16x4*>(smem + byte) = ov;
    }
    __syncthreads();

    // ---- MFMA: wave w owns C row-panel I = w; A-fragments cached in regs ----
    const int I    = w;
    const int lrow = lane & 15;
    const int kq   = lane >> 4;                // 0..3
    const int nkmax = (I + 2) >> 1;
    const int arow  = I * 16 + lrow;

    short8 a0 = {0,0,0,0,0,0,0,0}, a1 = a0, a2 = a0, a3 = a0,
           a4 = a0, a5 = a0, a6 = a0, a7 = a0;
#define LOADA(K, AV) if (K < nkmax) { \
        int ab = (arow << 9) + ((K * 32 + kq * 8) << 1); ab ^= (arow & 7) << 4; \
        AV = *reinterpret_cast<const short8*>(smem + ab); }
    LOADA(0, a0) LOADA(1, a1) LOADA(2, a2) LOADA(3, a3)
    LOADA(4, a4) LOADA(5, a5) LOADA(6, a6) LOADA(7, a7)
#undef LOADA

    for (int J = 0; J < 16; ++J) {
        const int nk = ((I < J ? I : J) + 2) >> 1;
        f32x4 acc = {0.f, 0.f, 0.f, 0.f};
        const int brow = J * 16 + lrow;
#define STEP(K, AV) if (K < nk) { \
        int bb = (brow << 9) + ((K * 32 + kq * 8) << 1); bb ^= (brow & 7) << 4; \
        const short8 b = *reinterpret_cast<const short8*>(smem + bb); \
        acc = __builtin_amdgcn_mfma_f32_16x16x32_bf16(AV, b, acc, 0, 0, 0); }
        STEP(0, a0) STEP(1, a1) STEP(2, a2) STEP(3, a3)
        STEP(4, a4) STEP(5, a5) STEP(6, a6) STEP(7, a7)
#undef STEP
        const int crow = I * 16 + kq * 4;
        const int ccol = J * 16 + lrow;
#pragma unroll
        for (int q = 0; q < 4; ++q) {
            float vv = acc[q];
            if (crow + q == ccol) vv += 1e-6f;   // epsilon * I
            C[(crow + q) * NCH + ccol] = vv;
        }
    }
}

// ---------------------------------------------------------------------------
extern "C" void kernel_launch(void* const* d_in, const int* in_sizes, int n_in,
                              void* d_out, int out_size, void* d_ws, size_t ws_size,
                              hipStream_t stream) {
    const float* group_map = (const float*)d_in[0];   // (8,256,256) f32
    const float* dev       = (const float*)d_in[1];   // (64,8,32896) f32
    float* out  = (float*)d_out;                      // (64,8,256,256) f32
    float* t_ws = (float*)d_ws;                       // 8*32896 f32 = 1.05 MB

    (void)in_sizes; (void)n_in; (void)out_size; (void)ws_size;

    (void)hipFuncSetAttribute((const void*)syrk_kernel,
                              hipFuncAttributeMaxDynamicSharedMemorySize, 131072);

    chol_kernel<<<8, 1024, 0, stream>>>(group_map, t_ws);
    syrk_kernel<<<512, 1024, 131072, stream>>>(dev, t_ws, out);
}